// Round 8
// baseline (305.215 us; speedup 1.0000x reference)
//
#include <hip/hip_runtime.h>
#include <math.h>

// PerceptronGlia, G=1: one 64-lane wave per batch row (4096 waves -> 4
// waves/SIMD, 2x the TLP of the G=2 version). Lane l owns K consecutive
// positions in registers; K shrinks at every 64-width boundary
// (13x7,12,11,10,9,8,7,6,5 x32 for scan-1; 4,3,2,1 for scan-2) with
// wave-local LDS repacks. Cross-lane 3-tap halo via 2 __shfl_down/layer.
// Weights pre-transposed once into d_ws as [layer][chunk][lane][float4]
// (coalesced float4 loads, register double-buffered).

__device__ __forceinline__ float elu_f(float a) {
    return a > 0.0f ? a : (__expf(a) - 1.0f);
}

// ---- one scan layer, one row, in place ----
template<int K, int NW>
__device__ __forceinline__ void scan_layer_1(float (&h)[K], const float (&w)[NW]) {
    static_assert(NW >= 3 * K, "weight array too small");
    float e0 = __shfl_down(h[0], 1);                  // position K*(lane+1)
    float e1;
    if constexpr (K >= 2) e1 = __shfl_down(h[1], 1);  // position K*(lane+1)+1
    else                  e1 = __shfl_down(h[0], 2);
#pragma unroll
    for (int i = 0; i < K; ++i) {
        float x1 = (i + 1 < K) ? h[i + 1] : e0;
        float x2 = (i + 2 < K) ? h[i + 2] : ((i + 2 == K) ? e0 : e1);
        float a = fmaf(h[i], w[3 * i], fmaf(x1, w[3 * i + 1], x2 * w[3 * i + 2]));
        h[i] = elu_f(a);   // slot i+1 reads h[i+1..i+2]: not yet overwritten
    }
}

// ---- transposed-weight load: NC coalesced float4 per layer ----
template<int NC, int NW>
__device__ __forceinline__ void load_wt(float (&w)[NW], const float4* __restrict__ Tp,
                                        int lr) {
#pragma unroll
    for (int c = 0; c < NC; ++c) {
        float4 v = Tp[(size_t)lr * (NC * 64) + c * 64];
        w[4 * c + 0] = v.x; w[4 * c + 1] = v.y; w[4 * c + 2] = v.z; w[4 * c + 3] = v.w;
    }
}

template<int K, int NC>
__device__ __forceinline__ void scan_phase_1(const float* __restrict__ Tphase, int nl,
                                             int lane, float (&h)[K]) {
    const float4* __restrict__ Tp = reinterpret_cast<const float4*>(Tphase) + lane;
    float wa[4 * NC], wb[4 * NC];
    load_wt<NC>(wa, Tp, 0);
    int l = 0;
    for (; l + 2 <= nl; l += 2) {                    // wa holds layer l
        load_wt<NC>(wb, Tp, l + 1);
        scan_layer_1<K>(h, wa);
        if (l + 3 <= nl) load_wt<NC>(wa, Tp, l + 2);
        scan_layer_1<K>(h, wb);
    }
    if (l < nl) scan_layer_1<K>(h, wa);
}

// ---- state repack KA -> KB via wave-local LDS ----
template<int KA, int KB>
__device__ __forceinline__ void repack1(float (&a)[KA], float (&n)[KB],
                                        float* lds, int lane) {
    __syncthreads();
#pragma unroll
    for (int i = 0; i < KA; ++i) lds[KA * lane + i] = a[i];
    __syncthreads();
#pragma unroll
    for (int i = 0; i < KB; ++i) n[i] = lds[KB * lane + i];
    __syncthreads();
}

// ---- biased 3-tap layer, K=5 layout, zero-padded ends, one row ----
__device__ __forceinline__ void stage2_1(float (&h)[5], const float* __restrict__ Ws,
                                         const float* __restrict__ bs, int lane) {
#pragma unroll
    for (int i = 0; i < 5; ++i)
        if (5 * lane + i > 255) h[i] = 0.0f;
    float w0[5], w1[5], w2[5], bb[5];
#pragma unroll
    for (int i = 0; i < 5; ++i) {
        int j = 5 * lane + i;
        bool v = j < 256;
        w0[i] = v ? Ws[3 * j + 0] : 0.f;
        w1[i] = v ? Ws[3 * j + 1] : 0.f;
        w2[i] = v ? Ws[3 * j + 2] : 0.f;
        bb[i] = v ? bs[j] : 0.f;
    }
    float p = __shfl_up(h[4], 1); if (lane == 0) p = 0.0f;   // h[j-1] halo
    float q = __shfl_down(h[0], 1);                           // h[j+1] halo
    float y[5];
#pragma unroll
    for (int i = 0; i < 5; ++i) {        // reads left neighbor -> no in-place
        float xm = (i == 0) ? p : h[i - 1];
        float xp = (i == 4) ? q : h[i + 1];
        y[i] = elu_f(fmaf(xm, w0[i], fmaf(h[i], w1[i], fmaf(xp, w2[i], bb[i]))));
    }
#pragma unroll
    for (int i = 0; i < 5; ++i) h[i] = y[i];
}

// ---- final 10 logits + log-softmax (K=1: position = lane) ----
__device__ __forceinline__ void emit_row(float v, const float* __restrict__ Wl,
                                         float* __restrict__ out, int row, int lane) {
    float n1 = __shfl_down(v, 1);
    float n2 = __shfl_down(v, 2);
    float lg = 0.0f;
    if (lane < 10)
        lg = fmaf(v, Wl[3 * lane], fmaf(n1, Wl[3 * lane + 1], n2 * Wl[3 * lane + 2]));
    float t = (lane < 10) ? lg : -1e30f;
#pragma unroll
    for (int d = 1; d < 16; d <<= 1) t = fmaxf(t, __shfl_xor(t, d));
    float e = (lane < 10) ? __expf(lg - t) : 0.0f;
    float s = e;
#pragma unroll
    for (int d = 1; d < 16; d <<= 1) s += __shfl_xor(s, d);
    float lse = t + __logf(s);
    if (lane < 10) out[(size_t)row * 10 + lane] = lg - lse;
}

// ---- transposed-weight layout (floats), fine-K ladder ----
//  ph  K NC  l0  nl  base          (scan1: W0 lstride 2346; scan2: W2 762)
//  0  13 10   0   7  0
//  1  12  9   7  32  17920
//  2  11  9  39  32  91648
//  3  10  8  71  32  165376
//  4   9  7 103  32  230912
//  5   8  6 135  32  288256
//  6   7  6 167  32  337408
//  7   6  5 199  32  386560
//  8   5  4 231  32  427520
//  9   4  3   0  31  460288
// 10   3  3  31  32  484096
// 11   2  2  63  32  508672
// 12   1  1  95  26  525056
#define T_TOTAL 531712   // floats; 2,126,848 bytes

__global__ __launch_bounds__(256)
void reorder_w(const float* __restrict__ W0, const float* __restrict__ W2,
               float* __restrict__ T) {
    int idx = blockIdx.x * 256 + threadIdx.x;
    if (idx >= T_TOTAL) return;
    int base, l0, K, NC, s1;
    if      (idx < 17920)  { base = 0;      l0 = 0;   K = 13; NC = 10; s1 = 1; }
    else if (idx < 91648)  { base = 17920;  l0 = 7;   K = 12; NC = 9;  s1 = 1; }
    else if (idx < 165376) { base = 91648;  l0 = 39;  K = 11; NC = 9;  s1 = 1; }
    else if (idx < 230912) { base = 165376; l0 = 71;  K = 10; NC = 8;  s1 = 1; }
    else if (idx < 288256) { base = 230912; l0 = 103; K = 9;  NC = 7;  s1 = 1; }
    else if (idx < 337408) { base = 288256; l0 = 135; K = 8;  NC = 6;  s1 = 1; }
    else if (idx < 386560) { base = 337408; l0 = 167; K = 7;  NC = 6;  s1 = 1; }
    else if (idx < 427520) { base = 386560; l0 = 199; K = 6;  NC = 5;  s1 = 1; }
    else if (idx < 460288) { base = 427520; l0 = 231; K = 5;  NC = 4;  s1 = 1; }
    else if (idx < 484096) { base = 460288; l0 = 0;   K = 4;  NC = 3;  s1 = 0; }
    else if (idx < 508672) { base = 484096; l0 = 31;  K = 3;  NC = 3;  s1 = 0; }
    else if (idx < 525056) { base = 508672; l0 = 63;  K = 2;  NC = 2;  s1 = 0; }
    else                   { base = 525056; l0 = 95;  K = 1;  NC = 1;  s1 = 0; }
    const float* Wsrc = s1 ? W0 : W2;
    int lstride = s1 ? 2346 : 762;
    int rel  = idx - base;
    int perL = NC * 256;
    int lr   = rel / perL;
    int r2   = rel - lr * perL;
    int c    = r2 >> 8;
    int ln   = (r2 >> 2) & 63;
    int f    = r2 & 3;
    int elem = 4 * c + f;
    float v = 0.0f;
    if (elem < 3 * K) {
        int b = 3 * K * ln;
        if (b + 3 * K > lstride) b = lstride - 3 * K;  // clamped lanes are all-dead
        v = Wsrc[(size_t)(l0 + lr) * lstride + b + elem];
    }
    T[idx] = v;
}

// ---- main kernel: one wave per row ----
__global__ __launch_bounds__(64)
void pg_kernel_1(const float* __restrict__ x,  const float* __restrict__ Ws,
                 const float* __restrict__ bs, const float* __restrict__ Wlast,
                 const float* __restrict__ T,  float* __restrict__ out)
{
    __shared__ float lds[13 * 64];          // repack scratch, 3.3 KB
    const int lane = threadIdx.x;
    const int row  = blockIdx.x;
    const float* __restrict__ xr = x + (size_t)row * 784;

    float h13[13];
#pragma unroll
    for (int i = 0; i < 13; ++i) {
        int p = 13 * lane + i;
        h13[i] = (p < 784) ? xr[p] : 0.0f;
    }

    // ---- scan 1 (263 layers) ----
    scan_phase_1<13, 10>(T + 0,      7,  lane, h13);
    float h12[12]; repack1<13, 12>(h13, h12, lds, lane);
    scan_phase_1<12, 9>(T + 17920,   32, lane, h12);
    float h11[11]; repack1<12, 11>(h12, h11, lds, lane);
    scan_phase_1<11, 9>(T + 91648,   32, lane, h11);
    float h10[10]; repack1<11, 10>(h11, h10, lds, lane);
    scan_phase_1<10, 8>(T + 165376,  32, lane, h10);
    float h9[9];   repack1<10, 9>(h10, h9, lds, lane);
    scan_phase_1<9, 7>(T + 230912,   32, lane, h9);
    float h8[8];   repack1<9, 8>(h9, h8, lds, lane);
    scan_phase_1<8, 6>(T + 288256,   32, lane, h8);
    float h7[7];   repack1<8, 7>(h8, h7, lds, lane);
    scan_phase_1<7, 6>(T + 337408,   32, lane, h7);
    float h6[6];   repack1<7, 6>(h7, h6, lds, lane);
    scan_phase_1<6, 5>(T + 386560,   32, lane, h6);
    float h5[5];   repack1<6, 5>(h6, h5, lds, lane);
    scan_phase_1<5, 4>(T + 427520,   32, lane, h5);

    // ---- biased layer (width 256) ----
    stage2_1(h5, Ws, bs, lane);

    // ---- scan 2 (121 layers) ----
    float h4[4];   repack1<5, 4>(h5, h4, lds, lane);
    scan_phase_1<4, 3>(T + 460288,   31, lane, h4);
    float h3[3];   repack1<4, 3>(h4, h3, lds, lane);
    scan_phase_1<3, 3>(T + 484096,   32, lane, h3);
    float h2[2];   repack1<3, 2>(h3, h2, lds, lane);
    scan_phase_1<2, 2>(T + 508672,   32, lane, h2);
    float h1[1];   repack1<2, 1>(h2, h1, lds, lane);
    scan_phase_1<1, 1>(T + 525056,   26, lane, h1);

    emit_row(h1[0], Wlast, out, row, lane);
}

// ---- fallback kernel (direct gather, G=2 scalar — used only if ws too small) ----
template<int K>
__device__ __forceinline__ void scan_phase_s(const float* __restrict__ W, int lstride,
                                             int l0, int l1, int lane,
                                             float (&hA)[K], float (&hB)[K]) {
    int base = 3 * K * lane;
    if (base + 3 * K > lstride) base = lstride - 3 * K;
    const float* __restrict__ Wp = W + (size_t)l0 * lstride + base;
    float wa[3 * K];
    for (int l = l0; l < l1; ++l) {
#pragma unroll
        for (int j = 0; j < 3 * K; ++j) wa[j] = Wp[j];
        scan_layer_1<K>(hA, wa);
        scan_layer_1<K>(hB, wa);
        Wp += lstride;
    }
}
template<int KA, int KB>
__device__ __forceinline__ void repack_s(float (&aA)[KA], float (&aB)[KA],
                                         float (&nA)[KB], float (&nB)[KB],
                                         float* lds, int lane) {
    __syncthreads();
#pragma unroll
    for (int i = 0; i < KA; ++i) lds[KA * lane + i] = aA[i];
    __syncthreads();
#pragma unroll
    for (int i = 0; i < KB; ++i) nA[i] = lds[KB * lane + i];
    __syncthreads();
#pragma unroll
    for (int i = 0; i < KA; ++i) lds[KA * lane + i] = aB[i];
    __syncthreads();
#pragma unroll
    for (int i = 0; i < KB; ++i) nB[i] = lds[KB * lane + i];
    __syncthreads();
}
__global__ __launch_bounds__(64)
void pg_kernel_d(const float* __restrict__ x,  const float* __restrict__ W0,
                 const float* __restrict__ Ws, const float* __restrict__ bs,
                 const float* __restrict__ W2, const float* __restrict__ Wlast,
                 float* __restrict__ out)
{
    __shared__ float lds[13 * 64];
    const int lane = threadIdx.x;
    const int rowA = blockIdx.x * 2;
    const int rowB = rowA + 1;
    float a13[13], b13[13];
#pragma unroll
    for (int i = 0; i < 13; ++i) {
        int p = 13 * lane + i;
        a13[i] = (p < 784) ? x[(size_t)rowA * 784 + p] : 0.0f;
        b13[i] = (p < 784) ? x[(size_t)rowB * 784 + p] : 0.0f;
    }
    scan_phase_s<13>(W0, 2346, 0, 71, lane, a13, b13);
    float a10[10], b10[10]; repack_s<13, 10>(a13, b13, a10, b10, lds, lane);
    scan_phase_s<10>(W0, 2346, 71, 167, lane, a10, b10);
    float a7[7], b7[7];     repack_s<10, 7>(a10, b10, a7, b7, lds, lane);
    scan_phase_s<7>(W0, 2346, 167, 231, lane, a7, b7);
    float a5[5], b5[5];     repack_s<7, 5>(a7, b7, a5, b5, lds, lane);
    scan_phase_s<5>(W0, 2346, 231, 263, lane, a5, b5);
    stage2_1(a5, Ws, bs, lane);
    stage2_1(b5, Ws, bs, lane);
    float a4[4], b4[4];     repack_s<5, 4>(a5, b5, a4, b4, lds, lane);
    scan_phase_s<4>(W2, 762, 0, 31, lane, a4, b4);
    float a3[3], b3[3];     repack_s<4, 3>(a4, b4, a3, b3, lds, lane);
    scan_phase_s<3>(W2, 762, 31, 63, lane, a3, b3);
    float a2_[2], b2_[2];   repack_s<3, 2>(a3, b3, a2_, b2_, lds, lane);
    scan_phase_s<2>(W2, 762, 63, 95, lane, a2_, b2_);
    float a1[1], b1[1];     repack_s<2, 1>(a2_, b2_, a1, b1, lds, lane);
    scan_phase_s<1>(W2, 762, 95, 121, lane, a1, b1);
    emit_row(a1[0], Wlast, out, rowA, lane);
    emit_row(b1[0], Wlast, out, rowB, lane);
}

extern "C" void kernel_launch(void* const* d_in, const int* in_sizes, int n_in,
                              void* d_out, int out_size, void* d_ws, size_t ws_size,
                              hipStream_t stream) {
    const float* x     = (const float*)d_in[0];
    const float* W0    = (const float*)d_in[1];
    const float* Ws    = (const float*)d_in[2];
    const float* bs    = (const float*)d_in[3];
    const float* W2    = (const float*)d_in[4];
    const float* Wlast = (const float*)d_in[5];
    float* out = (float*)d_out;

    if (ws_size >= (size_t)T_TOTAL * sizeof(float)) {
        float* T = (float*)d_ws;
        reorder_w<<<(T_TOTAL + 255) / 256, 256, 0, stream>>>(W0, W2, T);
        pg_kernel_1<<<4096, 64, 0, stream>>>(x, Ws, bs, Wlast, T, out);
    } else {
        pg_kernel_d<<<2048, 64, 0, stream>>>(x, W0, Ws, bs, W2, Wlast, out);
    }
}